// Round 7
// baseline (484.128 us; speedup 1.0000x reference)
//
#include <hip/hip_runtime.h>
#include <math.h>

// Problem constants (match reference)
#define B_  4
#define NQ_ 8192
#define D_  256
#define H_  8
#define L_  4
#define K_  4
#define DH_ 32
#define NV_ 5440

// Padded value-slab geometry (per (b,h)): levels with 1-px zero border
// L0: 66x66=4356, L1: 34x34=1156, L2: 18x18=324, L3: 10x10=100 -> 5936 rows
#define SLAB_ 5936

typedef short bf16x8 __attribute__((ext_vector_type(8)));
typedef float f32x4  __attribute__((ext_vector_type(4)));
typedef float f32x8  __attribute__((ext_vector_type(8)));
typedef unsigned short u16x8 __attribute__((ext_vector_type(8)));

__device__ __forceinline__ ushort f2bf(float f) {
    union { float f; unsigned u; } v; v.f = f;
    return (ushort)((v.u + 0x7FFF + ((v.u >> 16) & 1)) >> 16);
}
__device__ __forceinline__ float bf2f(ushort u) {
    union { unsigned u; float f; } v; v.u = ((unsigned)u) << 16;
    return v.f;
}

// ---------------------------------------------------------------------------
// k_prep: slab zeroing + weight transposes (small, one launch)
//  [0,2968):      zero vperm slabs (16B/thread)
//  [2968,3224):   Wv transpose-convert -> Wvt
//  [3224,3480):   Wo transpose-convert -> Wot
//  [3480,3768):   {Wt|Wf|Wlv|Wp} transpose-convert -> Wqt
// ---------------------------------------------------------------------------
__global__ __launch_bounds__(256) void k_prep(const float* __restrict__ Wv,
                                              const float* __restrict__ Wo,
                                              const float* __restrict__ Wt,
                                              const float* __restrict__ Wf,
                                              const float* __restrict__ Wlv,
                                              const float* __restrict__ Wp,
                                              uint4* __restrict__ vzero,
                                              ushort* __restrict__ Wvt,
                                              ushort* __restrict__ Wot,
                                              ushort* __restrict__ Wqt) {
    const int bk = blockIdx.x;
    const int t  = threadIdx.x;
    if (bk < 2968) {
        vzero[(size_t)bk * 256 + t] = make_uint4(0, 0, 0, 0);
    } else if (bk < 3480) {
        const float* in; ushort* out; int n;
        if (bk < 3224) { in = Wv; out = Wvt; n = bk - 2968; }
        else           { in = Wo; out = Wot; n = bk - 3224; }
        out[n * 256 + t] = f2bf(in[t * 256 + n]);
    } else {
        const int n = bk - 3480;
        float v;
        if (n < 64)       v = Wt[t * 64 + n];
        else if (n < 128) v = Wf[t * 64 + (n - 64)];
        else if (n < 160) v = Wlv[t * 32 + (n - 128)];
        else              v = Wp[t * 128 + (n - 160)];
        Wqt[n * 256 + t] = f2bf(v);
    }
}

// ---------------------------------------------------------------------------
// MFMA GEMM (round-5 proven form): C = A[M][256] @ Bt[N][256]^T (+bias)
// tile 128 x 128, 4 waves 2x2, 16x16x32 bf16, BK=32, sync staging
// AF32: 1 = A is fp32 (convert on stage), 0 = A already bf16
// MODE 0: out proj -> f32 C[row*256+col] = acc + bias[col]
// MODE 1: vproj    -> bf16 padded slab write (zero-border layout)
// ---------------------------------------------------------------------------
template<int MODE, int AF32>
__global__ __launch_bounds__(256) void k_gemm(const void* __restrict__ Ap,
                                              const ushort* __restrict__ Bt,
                                              const float* __restrict__ bias,
                                              void* __restrict__ Cp) {
    constexpr int NT = 128;
    constexpr int NFN = 4;
    __shared__ ushort As[128 * 32];
    __shared__ ushort Bs[NT * 32];
    const int m0   = blockIdx.x * 128;
    const int n0   = blockIdx.y * NT;
    const int t    = threadIdx.x;
    const int w    = t >> 6;
    const int lane = t & 63;
    const int wm   = (w >> 1) * 64;
    const int wn   = (w & 1) * (NT / 2);
    const int lm   = lane & 15;
    const int quad = lane >> 4;

    f32x4 acc[4][NFN];
    #pragma unroll
    for (int i = 0; i < 4; ++i)
        #pragma unroll
        for (int j = 0; j < NFN; ++j)
            acc[i][j] = (f32x4)(0.f);

    for (int kc = 0; kc < 256; kc += 32) {
        __syncthreads();
        if (AF32) {
            const float* A = (const float*)Ap;
            #pragma unroll
            for (int i = 0; i < 4; ++i) {
                const int c   = t + i * 256;
                const int row = c >> 3, ko = (c & 7) * 4;
                const float4 v = *(const float4*)&A[(size_t)(m0 + row) * 256 + kc + ko];
                ushort4 u; u.x = f2bf(v.x); u.y = f2bf(v.y); u.z = f2bf(v.z); u.w = f2bf(v.w);
                *(ushort4*)&As[row * 32 + ko] = u;
            }
        } else {
            const ushort* A = (const ushort*)Ap;
            #pragma unroll
            for (int i = 0; i < 2; ++i) {
                const int c   = t + i * 256;
                const int row = c >> 2, ko = (c & 3) * 8;
                *(u16x8*)&As[row * 32 + ko] =
                    *(const u16x8*)&A[(size_t)(m0 + row) * 256 + kc + ko];
            }
        }
        #pragma unroll
        for (int i = 0; i < 2; ++i) {
            const int c = t + i * 256;
            const int row = c >> 2, ko = (c & 3) * 8;
            *(u16x8*)&Bs[row * 32 + ko] =
                *(const u16x8*)&Bt[(size_t)(n0 + row) * 256 + kc + ko];
        }
        __syncthreads();

        bf16x8 af[4], bfr[NFN];
        #pragma unroll
        for (int mf = 0; mf < 4; ++mf)
            af[mf] = *(const bf16x8*)&As[(wm + mf * 16 + lm) * 32 + quad * 8];
        #pragma unroll
        for (int nf = 0; nf < NFN; ++nf)
            bfr[nf] = *(const bf16x8*)&Bs[(wn + nf * 16 + lm) * 32 + quad * 8];
        #pragma unroll
        for (int mf = 0; mf < 4; ++mf)
            #pragma unroll
            for (int nf = 0; nf < NFN; ++nf)
                acc[mf][nf] = __builtin_amdgcn_mfma_f32_16x16x32_bf16(
                    af[mf], bfr[nf], acc[mf][nf], 0, 0, 0);
    }

    // epilogue store: C/D layout col=lane&15, row=quad*4+reg
    #pragma unroll
    for (int mf = 0; mf < 4; ++mf) {
        #pragma unroll
        for (int nf = 0; nf < NFN; ++nf) {
            const f32x4 a = acc[mf][nf];
            const int col   = n0 + wn + nf * 16 + lm;
            const int rbase = m0 + wm + mf * 16 + quad * 4;
            #pragma unroll
            for (int r = 0; r < 4; ++r) {
                const int row = rbase + r;
                const float v = a[r];
                if (MODE == 0) {
                    ((float*)Cp)[(size_t)row * 256 + col] = v + bias[col];
                } else {
                    const int b = row / NV_, s = row - b * NV_;
                    const int h = col >> 5, dh = col & 31;
                    const int l = (s >= 5376) ? 3 : (s >= 5120) ? 2 : (s >= 4096) ? 1 : 0;
                    const int lsi_[4] = {0, 4096, 5120, 5376};
                    const int po_[4]  = {0, 4356, 5512, 5836};
                    const int o  = s - lsi_[l];
                    const int Wl = 64 >> l;
                    const int y  = o >> (6 - l);
                    const int x  = o & (Wl - 1);
                    const int prow = po_[l] + (y + 1) * (Wl + 2) + (x + 1);
                    ((ushort*)Cp)[(((size_t)(b * H_ + h)) * SLAB_ + prow) * 32 + dh] =
                        f2bf(v + bias[col]);
                }
            }
        }
    }
}

// ---------------------------------------------------------------------------
// Fused query projection + epilogue: query f32 -> params, no logits roundtrip
// tile M=64 x N=288, 4 waves 2x2 (wm in {0,32}, wn in {0,144}), BK=32
// After K-loop: 2 phases of 32 rows through LDS -> tanh/softmax/coords
// params per (b,q): [H][L][8] = {attn0..3, xA, xB, yA, yB}
// ---------------------------------------------------------------------------
__global__ __launch_bounds__(256) void k_qproj(const float* __restrict__ query,
                                               const ushort* __restrict__ Wqt,
                                               const float* __restrict__ refpts,
                                               const float* __restrict__ bt,
                                               const float* __restrict__ bfq,
                                               const float* __restrict__ blv,
                                               const float* __restrict__ bp,
                                               float* __restrict__ params) {
    // smem: staging (64*32 + 288*32)*2 = 22528 B; epilogue 32*296*4 = 37888 B
    __shared__ __align__(16) char smem[37888];
    ushort* As = (ushort*)smem;
    ushort* Bs = As + 64 * 32;
    float*  ep = (float*)smem;

    const int m0   = blockIdx.x * 64;
    const int t    = threadIdx.x;
    const int w    = t >> 6;
    const int lane = t & 63;
    const int wm   = (w >> 1) * 32;
    const int wn   = (w & 1) * 144;
    const int lm   = lane & 15;
    const int quad = lane >> 4;

    f32x4 acc[2][9];
    #pragma unroll
    for (int i = 0; i < 2; ++i)
        #pragma unroll
        for (int j = 0; j < 9; ++j)
            acc[i][j] = (f32x4)(0.f);

    for (int kc = 0; kc < 256; kc += 32) {
        __syncthreads();
        // A: 64 rows x 32 k from f32 query (512 float4 chunks, 2/thread)
        #pragma unroll
        for (int i = 0; i < 2; ++i) {
            const int c   = t + i * 256;
            const int row = c >> 3, ko = (c & 7) * 4;
            const float4 v = *(const float4*)&query[(size_t)(m0 + row) * 256 + kc + ko];
            ushort4 u; u.x = f2bf(v.x); u.y = f2bf(v.y); u.z = f2bf(v.z); u.w = f2bf(v.w);
            *(ushort4*)&As[row * 32 + ko] = u;
        }
        // B: 288 rows x 32 k bf16 (1152 16B chunks, guarded 5/thread)
        #pragma unroll
        for (int i = 0; i < 5; ++i) {
            const int c = t + i * 256;
            if (c < 1152) {
                const int row = c >> 2, ko = (c & 3) * 8;
                *(u16x8*)&Bs[row * 32 + ko] =
                    *(const u16x8*)&Wqt[(size_t)row * 256 + kc + ko];
            }
        }
        __syncthreads();

        bf16x8 af[2], bfr[9];
        #pragma unroll
        for (int mf = 0; mf < 2; ++mf)
            af[mf] = *(const bf16x8*)&As[(wm + mf * 16 + lm) * 32 + quad * 8];
        #pragma unroll
        for (int nf = 0; nf < 9; ++nf)
            bfr[nf] = *(const bf16x8*)&Bs[(wn + nf * 16 + lm) * 32 + quad * 8];
        #pragma unroll
        for (int mf = 0; mf < 2; ++mf)
            #pragma unroll
            for (int nf = 0; nf < 9; ++nf)
                acc[mf][nf] = __builtin_amdgcn_mfma_f32_16x16x32_bf16(
                    af[mf], bfr[nf], acc[mf][nf], 0, 0, 0);
    }

    // ---- fused epilogue: two phases of 32 q-rows through LDS
    #pragma unroll
    for (int ph = 0; ph < 2; ++ph) {
        __syncthreads();
        if ((w >> 1) == ph) {
            #pragma unroll
            for (int mf = 0; mf < 2; ++mf)
                #pragma unroll
                for (int nf = 0; nf < 9; ++nf)
                    #pragma unroll
                    for (int r = 0; r < 4; ++r)
                        ep[(mf * 16 + quad * 4 + r) * 296 + wn + nf * 16 + lm]
                            = acc[mf][nf][r];
        }
        __syncthreads();
        // 32 rows x 32 hl = 1024 items, 4 per thread
        #pragma unroll
        for (int it = 0; it < 4; ++it) {
            const int item = t + it * 256;
            const int qr = item >> 5;
            const int hl = item & 31;
            const int h = hl >> 2, l = hl & 3;
            const int qg = m0 + ph * 32 + qr;
            const float* lgr = &ep[qr * 296];

            const float tA = tanhf(lgr[hl * 2 + 0] + bt[hl * 2 + 0]);
            const float tB = tanhf(lgr[hl * 2 + 1] + bt[hl * 2 + 1]);
            const float fA = tanhf(lgr[64 + hl * 2 + 0] + bfq[hl * 2 + 0]);
            const float fB = tanhf(lgr[64 + hl * 2 + 1] + bfq[hl * 2 + 1]);

            const float l0 = lgr[128 + h * 4 + 0] + blv[h * 4 + 0];
            const float l1 = lgr[128 + h * 4 + 1] + blv[h * 4 + 1];
            const float l2 = lgr[128 + h * 4 + 2] + blv[h * 4 + 2];
            const float l3 = lgr[128 + h * 4 + 3] + blv[h * 4 + 3];
            const float lmx = fmaxf(fmaxf(l0, l1), fmaxf(l2, l3));
            const float e0 = __expf(l0 - lmx), e1 = __expf(l1 - lmx);
            const float e2 = __expf(l2 - lmx), e3 = __expf(l3 - lmx);
            const float lsum = e0 + e1 + e2 + e3;
            const float lwv = ((l == 0) ? e0 : (l == 1) ? e1 : (l == 2) ? e2 : e3) / lsum;

            const float p0 = lgr[160 + hl * 4 + 0] + bp[hl * 4 + 0];
            const float p1 = lgr[160 + hl * 4 + 1] + bp[hl * 4 + 1];
            const float p2 = lgr[160 + hl * 4 + 2] + bp[hl * 4 + 2];
            const float p3 = lgr[160 + hl * 4 + 3] + bp[hl * 4 + 3];
            const float pmx = fmaxf(fmaxf(p0, p1), fmaxf(p2, p3));
            const float q0e = __expf(p0 - pmx), q1e = __expf(p1 - pmx);
            const float q2e = __expf(p2 - pmx), q3e = __expf(p3 - pmx);
            const float inv = lwv / (q0e + q1e + q2e + q3e);

            const float rx = refpts[((size_t)qg * L_ + l) * 2 + 0];
            const float ry = refpts[((size_t)qg * L_ + l) * 2 + 1];
            const float Wlf = (float)(64 >> l);
            const float Hlf = (float)(64 >> l);
            const float xA = fminf(fmaxf(rx + tA / Wlf, 0.f), 1.f) * Wlf - 0.5f;
            const float xB = fminf(fmaxf(rx + tB / Wlf, 0.f), 1.f) * Wlf - 0.5f;
            const float yA = fminf(fmaxf(ry + fA / Hlf, 0.f), 1.f) * Hlf - 0.5f;
            const float yB = fminf(fmaxf(ry + fB / Hlf, 0.f), 1.f) * Hlf - 0.5f;

            float* pp = params + (size_t)qg * 256 + hl * 8;
            pp[0] = q0e * inv; pp[1] = q1e * inv; pp[2] = q2e * inv; pp[3] = q3e * inv;
            pp[4] = xA; pp[5] = xB; pp[6] = yA; pp[7] = yB;
        }
    }
}

// ---------------------------------------------------------------------------
// Bilinear sampling + attention accumulation -> mid bf16 [B*NQ][256]
// Thread = (ql, h, dh8); 16B gather loads; launch_bounds caps VGPR ~102
// ---------------------------------------------------------------------------
__global__ __launch_bounds__(256, 5) void k_sample(const ushort* __restrict__ vperm,
                                                   const float* __restrict__ params,
                                                   ushort* __restrict__ mid) {
    __shared__ float pm[8][264];   // per q: [h][33] padded
    const int b   = blockIdx.y;
    const int q0  = blockIdx.x * 8;
    const int t   = threadIdx.x;
    const int ql  = t >> 5;
    const int sub = t & 31;
    const int h   = sub >> 2;
    const int dh8 = sub & 3;

    for (int i = t; i < 8 * 256; i += 256) {
        const int q = i >> 8, c = i & 255;
        pm[q][(c >> 5) * 33 + (c & 31)] = params[((size_t)(b * NQ_ + q0 + q)) * 256 + c];
    }
    __syncthreads();

    const ushort* vb = vperm + ((size_t)(b * H_ + h)) * SLAB_ * 32 + dh8 * 8;
    const int po_[4] = {0, 4356, 5512, 5836};

    f32x8 acc = (f32x8)(0.f);
    #pragma unroll
    for (int l = 0; l < L_; ++l) {
        const int W2 = (64 >> l) + 2;
        const ushort* vl = vb + (size_t)po_[l] * 32;
        const float* p  = &pm[ql][h * 33 + l * 8];
        const float a0 = p[0], a1 = p[1], a2 = p[2], a3 = p[3];
        const float xA = p[4], xB = p[5], yA = p[6], yB = p[7];
        const float xa0 = floorf(xA), xb0 = floorf(xB);
        const float ya0 = floorf(yA), yb0 = floorf(yB);
        const float fxa = xA - xa0, fxb = xB - xb0;
        const float fya = yA - ya0, fyb = yB - yb0;
        const int pxa = (int)xa0 + 1, pxb = (int)xb0 + 1;
        const int pya = (int)ya0 + 1, pyb = (int)yb0 + 1;
        #pragma unroll
        for (int k = 0; k < 4; ++k) {
            const int   px = (k & 2) ? pxb : pxa;
            const int   py = (k & 1) ? pyb : pya;
            const float fx = (k & 2) ? fxb : fxa;
            const float fy = (k & 1) ? fyb : fya;
            const float ak = (k == 0) ? a0 : (k == 1) ? a1 : (k == 2) ? a2 : a3;
            const ushort* cp = vl + (size_t)(py * W2 + px) * 32;
            const u16x8 u00 = *(const u16x8*)cp;
            const u16x8 u10 = *(const u16x8*)(cp + 32);
            const u16x8 u01 = *(const u16x8*)(cp + W2 * 32);
            const u16x8 u11 = *(const u16x8*)(cp + (W2 + 1) * 32);
            const float gx = 1.f - fx, gy = 1.f - fy;
            const float w00 = ak * gx * gy, w10 = ak * fx * gy;
            const float w01 = ak * gx * fy, w11 = ak * fx * fy;
            #pragma unroll
            for (int e = 0; e < 8; ++e)
                acc[e] += bf2f(u00[e]) * w00 + bf2f(u10[e]) * w10
                        + bf2f(u01[e]) * w01 + bf2f(u11[e]) * w11;
        }
    }
    u16x8 o;
    #pragma unroll
    for (int e = 0; e < 8; ++e) o[e] = f2bf(acc[e]);
    *(u16x8*)&mid[((size_t)(b * NQ_ + q0 + ql)) * 256 + sub * 8] = o;
}

// ---------------------------------------------------------------------------
extern "C" void kernel_launch(void* const* d_in, const int* in_sizes, int n_in,
                              void* d_out, int out_size, void* d_ws, size_t ws_size,
                              hipStream_t stream) {
    const float* query = (const float*)d_in[0];
    const float* refp  = (const float*)d_in[1];
    const float* value = (const float*)d_in[2];
    const float* Wt = (const float*)d_in[5];
    const float* bt = (const float*)d_in[6];
    const float* Wf = (const float*)d_in[7];
    const float* bf = (const float*)d_in[8];
    const float* Wl = (const float*)d_in[9];
    const float* bl = (const float*)d_in[10];
    const float* Wp = (const float*)d_in[11];
    const float* bp = (const float*)d_in[12];
    const float* Wv = (const float*)d_in[13];
    const float* bv = (const float*)d_in[14];
    const float* Wo = (const float*)d_in[15];
    const float* bo = (const float*)d_in[16];

    // ws layout (all offsets 16B aligned)
    char* wsb = (char*)d_ws;
    ushort* vperm  = (ushort*)wsb;                       // 12,156,928 B
    float*  params = (float*)(wsb + 12156928);           // 33,554,432 B
    ushort* midb   = (ushort*)(wsb + 45711360);          // 16,777,216 B
    ushort* Wvt    = (ushort*)(wsb + 62488576);          // 131,072 B
    ushort* Wot    = (ushort*)(wsb + 62619648);          // 131,072 B
    ushort* Wqt    = (ushort*)(wsb + 62750720);          // 147,456 B

    // slab zeroing + weight transposes
    k_prep<<<3768, 256, 0, stream>>>(Wv, Wo, Wt, Wf, Wl, Wp,
                                     (uint4*)vperm, Wvt, Wot, Wqt);
    // value projection (f32 A) -> padded bf16 slabs
    k_gemm<1, 1><<<dim3(170, 2), 256, 0, stream>>>(value, Wvt, bv, vperm);
    // fused query projection + epilogue -> params
    k_qproj<<<512, 256, 0, stream>>>(query, Wqt, refp, bt, bf, bl, bp, params);
    // bilinear sampling + attention -> bf16 mid
    k_sample<<<dim3(NQ_ / 8, B_), 256, 0, stream>>>(vperm, params, midb);
    // output projection (bf16 A)
    k_gemm<0, 0><<<dim3(256, 2), 256, 0, stream>>>(midb, Wot, bo, (float*)d_out);
}

// Round 8
// 236.045 us; speedup vs baseline: 2.0510x; 2.0510x over previous
//
#include <hip/hip_runtime.h>
#include <math.h>

// Problem constants (match reference)
#define B_  4
#define NQ_ 8192
#define D_  256
#define H_  8
#define L_  4
#define K_  4
#define DH_ 32
#define NV_ 5440

// Padded value-slab geometry (per (b,h)): levels with 1-px zero border
// L0: 66x66=4356, L1: 34x34=1156, L2: 18x18=324, L3: 10x10=100 -> 5936 rows
#define SLAB_ 5936

typedef short bf16x8 __attribute__((ext_vector_type(8)));
typedef float f32x4  __attribute__((ext_vector_type(4)));
typedef float f32x8  __attribute__((ext_vector_type(8)));
typedef unsigned short u16x8 __attribute__((ext_vector_type(8)));

__device__ __forceinline__ ushort f2bf(float f) {
    union { float f; unsigned u; } v; v.f = f;
    return (ushort)((v.u + 0x7FFF + ((v.u >> 16) & 1)) >> 16);
}
__device__ __forceinline__ float bf2f(ushort u) {
    union { unsigned u; float f; } v; v.u = ((unsigned)u) << 16;
    return v.f;
}

// ---------------------------------------------------------------------------
// k_prep: slab zeroing + weight transposes (small, one launch)
//  [0,2968):      zero vperm slabs (16B/thread)
//  [2968,3224):   Wv transpose-convert -> Wvt
//  [3224,3480):   Wo transpose-convert -> Wot
//  [3480,3768):   {Wt|Wf|Wlv|Wp} transpose-convert -> Wqt
// ---------------------------------------------------------------------------
__global__ __launch_bounds__(256) void k_prep(const float* __restrict__ Wv,
                                              const float* __restrict__ Wo,
                                              const float* __restrict__ Wt,
                                              const float* __restrict__ Wf,
                                              const float* __restrict__ Wlv,
                                              const float* __restrict__ Wp,
                                              uint4* __restrict__ vzero,
                                              ushort* __restrict__ Wvt,
                                              ushort* __restrict__ Wot,
                                              ushort* __restrict__ Wqt) {
    const int bk = blockIdx.x;
    const int t  = threadIdx.x;
    if (bk < 2968) {
        vzero[(size_t)bk * 256 + t] = make_uint4(0, 0, 0, 0);
    } else if (bk < 3480) {
        const float* in; ushort* out; int n;
        if (bk < 3224) { in = Wv; out = Wvt; n = bk - 2968; }
        else           { in = Wo; out = Wot; n = bk - 3224; }
        out[n * 256 + t] = f2bf(in[t * 256 + n]);
    } else {
        const int n = bk - 3480;
        float v;
        if (n < 64)       v = Wt[t * 64 + n];
        else if (n < 128) v = Wf[t * 64 + (n - 64)];
        else if (n < 160) v = Wlv[t * 32 + (n - 128)];
        else              v = Wp[t * 128 + (n - 160)];
        Wqt[n * 256 + t] = f2bf(v);
    }
}

// ---------------------------------------------------------------------------
// MFMA GEMM (round-5 proven form): C = A[M][256] @ Bt[N][256]^T (+bias)
// tile 128 x 128, 4 waves 2x2, 16x16x32 bf16, BK=32, sync staging
// AF32: 1 = A is fp32 (convert on stage), 0 = A already bf16
// MODE 0: out proj -> f32 C[row*256+col] = acc + bias[col]
// MODE 1: vproj    -> bf16 padded slab write (zero-border layout)
// ---------------------------------------------------------------------------
template<int MODE, int AF32>
__global__ __launch_bounds__(256) void k_gemm(const void* __restrict__ Ap,
                                              const ushort* __restrict__ Bt,
                                              const float* __restrict__ bias,
                                              void* __restrict__ Cp) {
    constexpr int NT = 128;
    constexpr int NFN = 4;
    __shared__ ushort As[128 * 32];
    __shared__ ushort Bs[NT * 32];
    const int m0   = blockIdx.x * 128;
    const int n0   = blockIdx.y * NT;
    const int t    = threadIdx.x;
    const int w    = t >> 6;
    const int lane = t & 63;
    const int wm   = (w >> 1) * 64;
    const int wn   = (w & 1) * (NT / 2);
    const int lm   = lane & 15;
    const int quad = lane >> 4;

    f32x4 acc[4][NFN];
    #pragma unroll
    for (int i = 0; i < 4; ++i)
        #pragma unroll
        for (int j = 0; j < NFN; ++j)
            acc[i][j] = (f32x4)(0.f);

    for (int kc = 0; kc < 256; kc += 32) {
        __syncthreads();
        if (AF32) {
            const float* A = (const float*)Ap;
            #pragma unroll
            for (int i = 0; i < 4; ++i) {
                const int c   = t + i * 256;
                const int row = c >> 3, ko = (c & 7) * 4;
                const float4 v = *(const float4*)&A[(size_t)(m0 + row) * 256 + kc + ko];
                ushort4 u; u.x = f2bf(v.x); u.y = f2bf(v.y); u.z = f2bf(v.z); u.w = f2bf(v.w);
                *(ushort4*)&As[row * 32 + ko] = u;
            }
        } else {
            const ushort* A = (const ushort*)Ap;
            #pragma unroll
            for (int i = 0; i < 2; ++i) {
                const int c   = t + i * 256;
                const int row = c >> 2, ko = (c & 3) * 8;
                *(u16x8*)&As[row * 32 + ko] =
                    *(const u16x8*)&A[(size_t)(m0 + row) * 256 + kc + ko];
            }
        }
        #pragma unroll
        for (int i = 0; i < 2; ++i) {
            const int c = t + i * 256;
            const int row = c >> 2, ko = (c & 3) * 8;
            *(u16x8*)&Bs[row * 32 + ko] =
                *(const u16x8*)&Bt[(size_t)(n0 + row) * 256 + kc + ko];
        }
        __syncthreads();

        bf16x8 af[4], bfr[NFN];
        #pragma unroll
        for (int mf = 0; mf < 4; ++mf)
            af[mf] = *(const bf16x8*)&As[(wm + mf * 16 + lm) * 32 + quad * 8];
        #pragma unroll
        for (int nf = 0; nf < NFN; ++nf)
            bfr[nf] = *(const bf16x8*)&Bs[(wn + nf * 16 + lm) * 32 + quad * 8];
        #pragma unroll
        for (int mf = 0; mf < 4; ++mf)
            #pragma unroll
            for (int nf = 0; nf < NFN; ++nf)
                acc[mf][nf] = __builtin_amdgcn_mfma_f32_16x16x32_bf16(
                    af[mf], bfr[nf], acc[mf][nf], 0, 0, 0);
    }

    // epilogue store: C/D layout col=lane&15, row=quad*4+reg
    #pragma unroll
    for (int mf = 0; mf < 4; ++mf) {
        #pragma unroll
        for (int nf = 0; nf < NFN; ++nf) {
            const f32x4 a = acc[mf][nf];
            const int col   = n0 + wn + nf * 16 + lm;
            const int rbase = m0 + wm + mf * 16 + quad * 4;
            #pragma unroll
            for (int r = 0; r < 4; ++r) {
                const int row = rbase + r;
                const float v = a[r];
                if (MODE == 0) {
                    ((float*)Cp)[(size_t)row * 256 + col] = v + bias[col];
                } else {
                    const int b = row / NV_, s = row - b * NV_;
                    const int h = col >> 5, dh = col & 31;
                    const int l = (s >= 5376) ? 3 : (s >= 5120) ? 2 : (s >= 4096) ? 1 : 0;
                    const int lsi_[4] = {0, 4096, 5120, 5376};
                    const int po_[4]  = {0, 4356, 5512, 5836};
                    const int o  = s - lsi_[l];
                    const int Wl = 64 >> l;
                    const int y  = o >> (6 - l);
                    const int x  = o & (Wl - 1);
                    const int prow = po_[l] + (y + 1) * (Wl + 2) + (x + 1);
                    ((ushort*)Cp)[(((size_t)(b * H_ + h)) * SLAB_ + prow) * 32 + dh] =
                        f2bf(v + bias[col]);
                }
            }
        }
    }
}

// ---------------------------------------------------------------------------
// Fused query projection + epilogue: query f32 -> params, no logits roundtrip
// tile M=64 x N=288, 4 waves 2x2 (wm in {0,32}, wn in {0,144}), BK=32
// After K-loop: 2 phases of 32 rows through LDS -> tanh/softmax/coords
// params per (b,q): [H][L][8] = {attn0..3, xA, xB, yA, yB}
// ---------------------------------------------------------------------------
__global__ __launch_bounds__(256) void k_qproj(const float* __restrict__ query,
                                               const ushort* __restrict__ Wqt,
                                               const float* __restrict__ refpts,
                                               const float* __restrict__ bt,
                                               const float* __restrict__ bfq,
                                               const float* __restrict__ blv,
                                               const float* __restrict__ bp,
                                               float* __restrict__ params) {
    // smem: staging (64*32 + 288*32)*2 = 22528 B; epilogue 32*296*4 = 37888 B
    __shared__ __align__(16) char smem[37888];
    ushort* As = (ushort*)smem;
    ushort* Bs = As + 64 * 32;
    float*  ep = (float*)smem;

    const int m0   = blockIdx.x * 64;
    const int t    = threadIdx.x;
    const int w    = t >> 6;
    const int lane = t & 63;
    const int wm   = (w >> 1) * 32;
    const int wn   = (w & 1) * 144;
    const int lm   = lane & 15;
    const int quad = lane >> 4;

    f32x4 acc[2][9];
    #pragma unroll
    for (int i = 0; i < 2; ++i)
        #pragma unroll
        for (int j = 0; j < 9; ++j)
            acc[i][j] = (f32x4)(0.f);

    for (int kc = 0; kc < 256; kc += 32) {
        __syncthreads();
        // A: 64 rows x 32 k from f32 query (512 float4 chunks, 2/thread)
        #pragma unroll
        for (int i = 0; i < 2; ++i) {
            const int c   = t + i * 256;
            const int row = c >> 3, ko = (c & 7) * 4;
            const float4 v = *(const float4*)&query[(size_t)(m0 + row) * 256 + kc + ko];
            ushort4 u; u.x = f2bf(v.x); u.y = f2bf(v.y); u.z = f2bf(v.z); u.w = f2bf(v.w);
            *(ushort4*)&As[row * 32 + ko] = u;
        }
        // B: 288 rows x 32 k bf16 (1152 16B chunks, guarded 5/thread)
        #pragma unroll
        for (int i = 0; i < 5; ++i) {
            const int c = t + i * 256;
            if (c < 1152) {
                const int row = c >> 2, ko = (c & 3) * 8;
                *(u16x8*)&Bs[row * 32 + ko] =
                    *(const u16x8*)&Wqt[(size_t)row * 256 + kc + ko];
            }
        }
        __syncthreads();

        bf16x8 af[2], bfr[9];
        #pragma unroll
        for (int mf = 0; mf < 2; ++mf)
            af[mf] = *(const bf16x8*)&As[(wm + mf * 16 + lm) * 32 + quad * 8];
        #pragma unroll
        for (int nf = 0; nf < 9; ++nf)
            bfr[nf] = *(const bf16x8*)&Bs[(wn + nf * 16 + lm) * 32 + quad * 8];
        #pragma unroll
        for (int mf = 0; mf < 2; ++mf)
            #pragma unroll
            for (int nf = 0; nf < 9; ++nf)
                acc[mf][nf] = __builtin_amdgcn_mfma_f32_16x16x32_bf16(
                    af[mf], bfr[nf], acc[mf][nf], 0, 0, 0);
    }

    // ---- fused epilogue: two phases of 32 q-rows through LDS
    #pragma unroll
    for (int ph = 0; ph < 2; ++ph) {
        __syncthreads();
        if ((w >> 1) == ph) {
            #pragma unroll
            for (int mf = 0; mf < 2; ++mf)
                #pragma unroll
                for (int nf = 0; nf < 9; ++nf)
                    #pragma unroll
                    for (int r = 0; r < 4; ++r)
                        ep[(mf * 16 + quad * 4 + r) * 296 + wn + nf * 16 + lm]
                            = acc[mf][nf][r];
        }
        __syncthreads();
        // 32 rows x 32 hl = 1024 items, 4 per thread
        #pragma unroll
        for (int it = 0; it < 4; ++it) {
            const int item = t + it * 256;
            const int qr = item >> 5;
            const int hl = item & 31;
            const int h = hl >> 2, l = hl & 3;
            const int qg = m0 + ph * 32 + qr;
            const float* lgr = &ep[qr * 296];

            const float tA = tanhf(lgr[hl * 2 + 0] + bt[hl * 2 + 0]);
            const float tB = tanhf(lgr[hl * 2 + 1] + bt[hl * 2 + 1]);
            const float fA = tanhf(lgr[64 + hl * 2 + 0] + bfq[hl * 2 + 0]);
            const float fB = tanhf(lgr[64 + hl * 2 + 1] + bfq[hl * 2 + 1]);

            const float l0 = lgr[128 + h * 4 + 0] + blv[h * 4 + 0];
            const float l1 = lgr[128 + h * 4 + 1] + blv[h * 4 + 1];
            const float l2 = lgr[128 + h * 4 + 2] + blv[h * 4 + 2];
            const float l3 = lgr[128 + h * 4 + 3] + blv[h * 4 + 3];
            const float lmx = fmaxf(fmaxf(l0, l1), fmaxf(l2, l3));
            const float e0 = __expf(l0 - lmx), e1 = __expf(l1 - lmx);
            const float e2 = __expf(l2 - lmx), e3 = __expf(l3 - lmx);
            const float lsum = e0 + e1 + e2 + e3;
            const float lwv = ((l == 0) ? e0 : (l == 1) ? e1 : (l == 2) ? e2 : e3) / lsum;

            const float p0 = lgr[160 + hl * 4 + 0] + bp[hl * 4 + 0];
            const float p1 = lgr[160 + hl * 4 + 1] + bp[hl * 4 + 1];
            const float p2 = lgr[160 + hl * 4 + 2] + bp[hl * 4 + 2];
            const float p3 = lgr[160 + hl * 4 + 3] + bp[hl * 4 + 3];
            const float pmx = fmaxf(fmaxf(p0, p1), fmaxf(p2, p3));
            const float q0e = __expf(p0 - pmx), q1e = __expf(p1 - pmx);
            const float q2e = __expf(p2 - pmx), q3e = __expf(p3 - pmx);
            const float inv = lwv / (q0e + q1e + q2e + q3e);

            const float rx = refpts[((size_t)qg * L_ + l) * 2 + 0];
            const float ry = refpts[((size_t)qg * L_ + l) * 2 + 1];
            const float Wlf = (float)(64 >> l);
            const float Hlf = (float)(64 >> l);
            const float xA = fminf(fmaxf(rx + tA / Wlf, 0.f), 1.f) * Wlf - 0.5f;
            const float xB = fminf(fmaxf(rx + tB / Wlf, 0.f), 1.f) * Wlf - 0.5f;
            const float yA = fminf(fmaxf(ry + fA / Hlf, 0.f), 1.f) * Hlf - 0.5f;
            const float yB = fminf(fmaxf(ry + fB / Hlf, 0.f), 1.f) * Hlf - 0.5f;

            float* pp = params + (size_t)qg * 256 + hl * 8;
            pp[0] = q0e * inv; pp[1] = q1e * inv; pp[2] = q2e * inv; pp[3] = q3e * inv;
            pp[4] = xA; pp[5] = xB; pp[6] = yA; pp[7] = yB;
        }
    }
}

// ---------------------------------------------------------------------------
// Bilinear sampling + attention accumulation -> mid bf16 [B*NQ][256]
// Thread = (ql, h, dh8); 16B gather loads. Round-6 form: NO min-waves bound
// (launch_bounds(256,5) forced VGPR 120->48 and spilled 1.3GB to scratch).
// ---------------------------------------------------------------------------
__global__ __launch_bounds__(256) void k_sample(const ushort* __restrict__ vperm,
                                                const float* __restrict__ params,
                                                ushort* __restrict__ mid) {
    __shared__ float pm[8][264];   // per q: [h][33] padded
    const int b   = blockIdx.y;
    const int q0  = blockIdx.x * 8;
    const int t   = threadIdx.x;
    const int ql  = t >> 5;
    const int sub = t & 31;
    const int h   = sub >> 2;
    const int dh8 = sub & 3;

    for (int i = t; i < 8 * 256; i += 256) {
        const int q = i >> 8, c = i & 255;
        pm[q][(c >> 5) * 33 + (c & 31)] = params[((size_t)(b * NQ_ + q0 + q)) * 256 + c];
    }
    __syncthreads();

    const ushort* vb = vperm + ((size_t)(b * H_ + h)) * SLAB_ * 32 + dh8 * 8;
    const int po_[4] = {0, 4356, 5512, 5836};

    f32x8 acc = (f32x8)(0.f);
    #pragma unroll
    for (int l = 0; l < L_; ++l) {
        const int W2 = (64 >> l) + 2;
        const ushort* vl = vb + (size_t)po_[l] * 32;
        const float* p  = &pm[ql][h * 33 + l * 8];
        const float a0 = p[0], a1 = p[1], a2 = p[2], a3 = p[3];
        const float xA = p[4], xB = p[5], yA = p[6], yB = p[7];
        const float xa0 = floorf(xA), xb0 = floorf(xB);
        const float ya0 = floorf(yA), yb0 = floorf(yB);
        const float fxa = xA - xa0, fxb = xB - xb0;
        const float fya = yA - ya0, fyb = yB - yb0;
        const int pxa = (int)xa0 + 1, pxb = (int)xb0 + 1;
        const int pya = (int)ya0 + 1, pyb = (int)yb0 + 1;
        #pragma unroll
        for (int k = 0; k < 4; ++k) {
            const int   px = (k & 2) ? pxb : pxa;
            const int   py = (k & 1) ? pyb : pya;
            const float fx = (k & 2) ? fxb : fxa;
            const float fy = (k & 1) ? fyb : fya;
            const float ak = (k == 0) ? a0 : (k == 1) ? a1 : (k == 2) ? a2 : a3;
            const ushort* cp = vl + (size_t)(py * W2 + px) * 32;
            const u16x8 u00 = *(const u16x8*)cp;
            const u16x8 u10 = *(const u16x8*)(cp + 32);
            const u16x8 u01 = *(const u16x8*)(cp + W2 * 32);
            const u16x8 u11 = *(const u16x8*)(cp + (W2 + 1) * 32);
            const float gx = 1.f - fx, gy = 1.f - fy;
            const float w00 = ak * gx * gy, w10 = ak * fx * gy;
            const float w01 = ak * gx * fy, w11 = ak * fx * fy;
            #pragma unroll
            for (int e = 0; e < 8; ++e)
                acc[e] += bf2f(u00[e]) * w00 + bf2f(u10[e]) * w10
                        + bf2f(u01[e]) * w01 + bf2f(u11[e]) * w11;
        }
    }
    u16x8 o;
    #pragma unroll
    for (int e = 0; e < 8; ++e) o[e] = f2bf(acc[e]);
    *(u16x8*)&mid[((size_t)(b * NQ_ + q0 + ql)) * 256 + sub * 8] = o;
}

// ---------------------------------------------------------------------------
extern "C" void kernel_launch(void* const* d_in, const int* in_sizes, int n_in,
                              void* d_out, int out_size, void* d_ws, size_t ws_size,
                              hipStream_t stream) {
    const float* query = (const float*)d_in[0];
    const float* refp  = (const float*)d_in[1];
    const float* value = (const float*)d_in[2];
    const float* Wt = (const float*)d_in[5];
    const float* bt = (const float*)d_in[6];
    const float* Wf = (const float*)d_in[7];
    const float* bf = (const float*)d_in[8];
    const float* Wl = (const float*)d_in[9];
    const float* bl = (const float*)d_in[10];
    const float* Wp = (const float*)d_in[11];
    const float* bp = (const float*)d_in[12];
    const float* Wv = (const float*)d_in[13];
    const float* bv = (const float*)d_in[14];
    const float* Wo = (const float*)d_in[15];
    const float* bo = (const float*)d_in[16];

    // ws layout (all offsets 16B aligned)
    char* wsb = (char*)d_ws;
    ushort* vperm  = (ushort*)wsb;                       // 12,156,928 B
    float*  params = (float*)(wsb + 12156928);           // 33,554,432 B
    ushort* midb   = (ushort*)(wsb + 45711360);          // 16,777,216 B
    ushort* Wvt    = (ushort*)(wsb + 62488576);          // 131,072 B
    ushort* Wot    = (ushort*)(wsb + 62619648);          // 131,072 B
    ushort* Wqt    = (ushort*)(wsb + 62750720);          // 147,456 B

    // slab zeroing + weight transposes
    k_prep<<<3768, 256, 0, stream>>>(Wv, Wo, Wt, Wf, Wl, Wp,
                                     (uint4*)vperm, Wvt, Wot, Wqt);
    // value projection (f32 A) -> padded bf16 slabs
    k_gemm<1, 1><<<dim3(170, 2), 256, 0, stream>>>(value, Wvt, bv, vperm);
    // fused query projection + epilogue -> params
    k_qproj<<<512, 256, 0, stream>>>(query, Wqt, refp, bt, bf, bl, bp, params);
    // bilinear sampling + attention -> bf16 mid
    k_sample<<<dim3(NQ_ / 8, B_), 256, 0, stream>>>(vperm, params, midb);
    // output projection (bf16 A)
    k_gemm<0, 0><<<dim3(256, 2), 256, 0, stream>>>(midb, Wot, bo, (float*)d_out);
}